// Round 7
// baseline (103.340 us; speedup 1.0000x reference)
//
#include <hip/hip_runtime.h>
#include <stdint.h>

#define DIM 256
#define NQ 8
#define NLAYERS 3
#define NPAIRS 4

typedef short bf16x8 __attribute__((ext_vector_type(8)));
typedef float f32x4 __attribute__((ext_vector_type(4)));

__device__ __forceinline__ unsigned short f2bf(float f) {
  uint32_t x = __builtin_bit_cast(uint32_t, f);
  uint32_t r = (x + 0x7FFFu + ((x >> 16) & 1u)) >> 16;  // RNE
  return (unsigned short)r;
}

// ---------------------------------------------------------------------------
// Kernel 1: build U (256x256 complex fp32), barrier-free, one WAVE per basis
// column, one column per 64-thread block (256 blocks -> 1 wave/CU chip-wide).
// Lane holds 4 amplitudes a = r*64 + lane. Wire w <-> bit (7-w) of a:
//   wire0 -> r bit1, wire1 -> r bit0 (in-register),
//   wire2..7 -> lane bits 5..0 (cross-lane via shfl_xor).
// Algebra verified in round 6 (passed, absmax unchanged).
// ---------------------------------------------------------------------------
__global__ __launch_bounds__(64) void build_U(const float* __restrict__ params,
                                              float* __restrict__ Ure,
                                              float* __restrict__ Uim) {
  const int lane = threadIdx.x;
  const int col = blockIdx.x;

  float ar[4], ai[4];
#pragma unroll
  for (int r = 0; r < 4; ++r) {
    ar[r] = (r * 64 + lane == col) ? 1.0f : 0.0f;
    ai[r] = 0.0f;
  }

  for (int layer = 0; layer < NLAYERS; ++layer) {
#pragma unroll
    for (int p = 0; p < NPAIRS; ++p) {
      const int base = (layer * NPAIRS + p) * 4;
      const float p0 = params[base + 0], p1 = params[base + 1];
      const float p2 = params[base + 2], p3 = params[base + 3];
      const int czm = (p == 1) ? 32 : (p == 2) ? 8 : 2;   // ctrl / RZ_i bit
      const int txr = (p == 1) ? 16 : (p == 2) ? 4 : 1;   // target xor / bit

      { // RZ(p0) on wire i = 2p
        float s0, c0;
        __sincosf(0.5f * p0, &s0, &c0);
        if (p == 0) {
#pragma unroll
          for (int r = 0; r < 4; ++r) {
            const float sg = (r >= 2) ? s0 : -s0;  // r bit1
            const float nr = ar[r] * c0 - ai[r] * sg;
            ai[r] = ar[r] * sg + ai[r] * c0;
            ar[r] = nr;
          }
        } else {
          const float sg = (lane & czm) ? s0 : -s0;
#pragma unroll
          for (int r = 0; r < 4; ++r) {
            const float nr = ar[r] * c0 - ai[r] * sg;
            ai[r] = ar[r] * sg + ai[r] * c0;
            ar[r] = nr;
          }
        }
      }
      { // RX(p1) on wire j = 2p+1
        float s0, c0;
        __sincosf(0.5f * p1, &s0, &c0);
        if (p == 0) {  // partner r^1
          float nr[4], ni[4];
#pragma unroll
          for (int r = 0; r < 4; ++r) {
            nr[r] = c0 * ar[r] + s0 * ai[r ^ 1];
            ni[r] = c0 * ai[r] - s0 * ar[r ^ 1];
          }
#pragma unroll
          for (int r = 0; r < 4; ++r) { ar[r] = nr[r]; ai[r] = ni[r]; }
        } else {  // partner lane^txr
#pragma unroll
          for (int r = 0; r < 4; ++r) {
            const float pr = __shfl_xor(ar[r], txr);
            const float pi = __shfl_xor(ai[r], txr);
            ar[r] = c0 * ar[r] + s0 * pi;
            ai[r] = c0 * ai[r] - s0 * pr;
          }
        }
      }
      { // CNOT(i -> j)
        if (p == 0) {  // ctrl r bit1: swap amp[2] <-> amp[3]
          const float tr = ar[2], ti = ai[2];
          ar[2] = ar[3]; ai[2] = ai[3];
          ar[3] = tr;    ai[3] = ti;
        } else {
#pragma unroll
          for (int r = 0; r < 4; ++r) {
            const float vr = __shfl_xor(ar[r], txr);
            const float vi = __shfl_xor(ai[r], txr);
            ar[r] = (lane & czm) ? vr : ar[r];
            ai[r] = (lane & czm) ? vi : ai[r];
          }
        }
      }
      { // RZ(p2) on wire j
        float s0, c0;
        __sincosf(0.5f * p2, &s0, &c0);
        if (p == 0) {
#pragma unroll
          for (int r = 0; r < 4; ++r) {
            const float sg = (r & 1) ? s0 : -s0;  // r bit0
            const float nr = ar[r] * c0 - ai[r] * sg;
            ai[r] = ar[r] * sg + ai[r] * c0;
            ar[r] = nr;
          }
        } else {
          const float sg = (lane & txr) ? s0 : -s0;
#pragma unroll
          for (int r = 0; r < 4; ++r) {
            const float nr = ar[r] * c0 - ai[r] * sg;
            ai[r] = ar[r] * sg + ai[r] * c0;
            ar[r] = nr;
          }
        }
      }
      { // RX(p3) on wire j
        float s0, c0;
        __sincosf(0.5f * p3, &s0, &c0);
        if (p == 0) {
          float nr[4], ni[4];
#pragma unroll
          for (int r = 0; r < 4; ++r) {
            nr[r] = c0 * ar[r] + s0 * ai[r ^ 1];
            ni[r] = c0 * ai[r] - s0 * ar[r ^ 1];
          }
#pragma unroll
          for (int r = 0; r < 4; ++r) { ar[r] = nr[r]; ai[r] = ni[r]; }
        } else {
#pragma unroll
          for (int r = 0; r < 4; ++r) {
            const float pr = __shfl_xor(ar[r], txr);
            const float pi = __shfl_xor(ai[r], txr);
            ar[r] = c0 * ar[r] + s0 * pi;
            ai[r] = c0 * ai[r] - s0 * pr;
          }
        }
      }
    }
  }
#pragma unroll
  for (int r = 0; r < 4; ++r) {
    Ure[(r * 64 + lane) * DIM + col] = ar[r];
    Uim[(r * 64 + lane) * DIM + col] = ai[r];
  }
}

// ---------------------------------------------------------------------------
// Kernel 2: A[n][k] = Re(U^H D U)[n][k], bf16, MFMA A-operand fragment order
// (verified rounds 2-6):
//   elem(n,k) -> ((((n>>4)*8 + (k>>5))*4 + ((k>>3)&3))*16 + (n&15))*8 + (k&7)
// 1024 threads/block: 4 m-chunks in parallel + LDS reduce.
// ---------------------------------------------------------------------------
__global__ __launch_bounds__(1024) void build_A(const float* __restrict__ Ure,
                                                const float* __restrict__ Uim,
                                                short* __restrict__ Af) {
  __shared__ float partial[4][DIM];
  const int n = blockIdx.x;
  const int kk = threadIdx.x & 255;
  const int mc = threadIdx.x >> 8;  // 0..3
  float acc = 0.0f;
  for (int m = mc * 64; m < mc * 64 + 64; ++m) {
    const float sgn = (m < 128) ? 1.0f : -1.0f;
    const float ukr = sgn * Ure[m * DIM + n];
    const float uki = sgn * Uim[m * DIM + n];
    acc = fmaf(ukr, Ure[m * DIM + kk], acc);
    acc = fmaf(uki, Uim[m * DIM + kk], acc);
  }
  partial[mc][kk] = acc;
  __syncthreads();
  if (mc == 0) {
    const float v = partial[0][kk] + partial[1][kk] + partial[2][kk] + partial[3][kk];
    const int off =
        ((((n >> 4) * 8 + (kk >> 5)) * 4 + ((kk >> 3) & 3)) * 16 + (n & 15)) * 8 +
        (kk & 7);
    Af[off] = (short)f2bf(v);
  }
}

// ---------------------------------------------------------------------------
// Kernel 3 (MFMA, 1-wave blocks, 4 batch-groups = 64 batch/wave, v3):
// Round-6 post-mortem: 32 KB LDS capped residency at 5 blocks/CU and
// waves_per_eu(1) blessed it -> chunk-boundary DMA latency fully exposed.
// v3: 16 KB chunks (32 n-rows, 8 chunks) -> LDS allows 10 blocks/CU;
// amdgpu_waves_per_eu(2) (VGPR cap 256 > ~200 live set, min 2 waves/EU)
// -> 8 waves/CU with grid 2048 = exactly 8 blocks/CU: two waves per SIMD
// cover each other's staging stalls. Per chunk: 64 MFMAs (~310 cyc) vs
// 16 KB L2 staging (~290 cyc) - balanced. Fragment layouts unchanged
// (verified rounds 2-6).
// ---------------------------------------------------------------------------
__global__ __launch_bounds__(64)
__attribute__((amdgpu_waves_per_eu(2)))
void qcnn_mfma(const float* __restrict__ x,
               const short* __restrict__ Af,
               float* __restrict__ out) {
  __shared__ short sA[8192];  // one 16 KB chunk: 32 n-rows x 256 k (bf16)
  const int lane = threadIdx.x;
  const int c = lane & 15;
  const int q = lane >> 4;
  const int lo = q & 1;
  const int hi = (q >> 1) & 1;
  const int bbase = blockIdx.x * 64;
  const char* Abytes = (const char*)Af;
  char* sAbytes = (char*)sA;

  // stage chunk 0 (overlaps with psi setup below)
#pragma unroll
  for (int i = 0; i < 16; ++i) {
    __builtin_amdgcn_global_load_lds(
        (const __attribute__((address_space(1))) uint32_t*)(Abytes + i * 1024 +
                                                            lane * 16),
        (__attribute__((address_space(3))) uint32_t*)(sAbytes + i * 1024), 16,
        0, 0);
  }

  bf16x8 psi[4][8];
  float ccg[4][4], ssg[4][4], hd[4][4];
#pragma unroll
  for (int G = 0; G < 4; ++G) {
    const int b = bbase + G * 16 + c;
    const float4* xv = (const float4*)(x + (size_t)b * 8);
    const float4 x0 = xv[0];
    const float4 x1 = xv[1];
    const float xs[8] = {x0.x, x0.y, x0.z, x0.w, x1.x, x1.y, x1.z, x1.w};
    float cc[8], ss[8];
#pragma unroll
    for (int u = 0; u < 8; ++u) {
      cc[u] = __cosf(0.5f * xs[u]);
      ss[u] = __sinf(0.5f * xs[u]);
    }
    // hs[j] = h[8*lo + j]
    float hs[8];
    {
      const float a = lo ? ss[4] : cc[4];
      const float b0 = a * cc[5], b1 = a * ss[5];
      const float c0 = b0 * cc[6], c1 = b0 * ss[6];
      const float c2 = b1 * cc[6], c3 = b1 * ss[6];
      hs[0] = c0 * cc[7]; hs[1] = c0 * ss[7];
      hs[2] = c1 * cc[7]; hs[3] = c1 * ss[7];
      hs[4] = c2 * cc[7]; hs[5] = c2 * ss[7];
      hs[6] = c3 * cc[7]; hs[7] = c3 * ss[7];
    }
    // gk[t] = g[2t + hi]
    float gk[8];
    {
      const float g3 = hi ? ss[3] : cc[3];
      const float d0 = cc[2] * g3, d1 = ss[2] * g3;
      const float e0 = cc[1] * d0, e1 = cc[1] * d1;
      const float e2 = ss[1] * d0, e3 = ss[1] * d1;
      gk[0] = cc[0] * e0; gk[1] = cc[0] * e1;
      gk[2] = cc[0] * e2; gk[3] = cc[0] * e3;
      gk[4] = ss[0] * e0; gk[5] = ss[0] * e1;
      gk[6] = ss[0] * e2; gk[7] = ss[0] * e3;
    }
    // hd[r] = h[8*hi + 4*lo + r]
    {
      const float head = (hi ? ss[4] : cc[4]) * (lo ? ss[5] : cc[5]);
      const float h0 = head * cc[6], h1 = head * ss[6];
      hd[G][0] = h0 * cc[7]; hd[G][1] = h0 * ss[7];
      hd[G][2] = h1 * cc[7]; hd[G][3] = h1 * ss[7];
    }
    // psi frag for k-block t: element j is psi_b[32t + 8q + j] = gk[t]*hs[j]
#pragma unroll
    for (int t = 0; t < 8; ++t) {
#pragma unroll
      for (int j = 0; j < 8; ++j) psi[G][t][j] = (short)f2bf(gk[t] * hs[j]);
    }
#pragma unroll
    for (int u = 0; u < 4; ++u) { ccg[G][u] = cc[u]; ssg[G][u] = ss[u]; }
  }

  float z[4] = {0.0f, 0.0f, 0.0f, 0.0f};

#pragma unroll
  for (int nc = 0; nc < 8; ++nc) {  // 8 chunks x 32 n-rows
    if (nc) {
      __syncthreads();  // WAR: prior ds_reads done before DMA overwrite
#pragma unroll
      for (int i = 0; i < 16; ++i) {
        __builtin_amdgcn_global_load_lds(
            (const __attribute__((address_space(1))) uint32_t*)(
                Abytes + nc * 16384 + i * 1024 + lane * 16),
            (__attribute__((address_space(3))) uint32_t*)(sAbytes + i * 1024),
            16, 0, 0);
      }
    }
    __syncthreads();  // RAW: staged chunk visible

#pragma unroll
    for (int nt = 0; nt < 2; ++nt) {
      f32x4 a0 = {0.f, 0.f, 0.f, 0.f};
      f32x4 a1 = {0.f, 0.f, 0.f, 0.f};
      f32x4 a2 = {0.f, 0.f, 0.f, 0.f};
      f32x4 a3 = {0.f, 0.f, 0.f, 0.f};
#pragma unroll
      for (int t = 0; t < 8; ++t) {
        const bf16x8 af =
            *(const bf16x8*)(sA + (nt * 4096 + t * 512 + lane * 8));
        a0 = __builtin_amdgcn_mfma_f32_16x16x32_bf16(af, psi[0][t], a0, 0, 0, 0);
        a1 = __builtin_amdgcn_mfma_f32_16x16x32_bf16(af, psi[1][t], a1, 0, 0, 0);
        a2 = __builtin_amdgcn_mfma_f32_16x16x32_bf16(af, psi[2][t], a2, 0, 0, 0);
        a3 = __builtin_amdgcn_mfma_f32_16x16x32_bf16(af, psi[3][t], a3, 0, 0, 0);
      }
      // rows n = (nc*2+nt)*16 + q*4 + r -> psi[b][n] = g[nc*2+nt] * hd[r]
      const int gi = nc * 2 + nt;  // compile-time
#pragma unroll
      for (int G = 0; G < 4; ++G) {
        const f32x4 av = (G == 0) ? a0 : (G == 1) ? a1 : (G == 2) ? a2 : a3;
        const float gv = ((gi & 8) ? ssg[G][0] : ccg[G][0]) *
                         ((gi & 4) ? ssg[G][1] : ccg[G][1]) *
                         ((gi & 2) ? ssg[G][2] : ccg[G][2]) *
                         ((gi & 1) ? ssg[G][3] : ccg[G][3]);
        const float dot = hd[G][0] * av[0] + hd[G][1] * av[1] +
                          hd[G][2] * av[2] + hd[G][3] * av[3];
        z[G] = fmaf(gv, dot, z[G]);
      }
    }
  }

  // reduce across the 4 q-groups (same col lives in lanes c, c+16, c+32, c+48)
#pragma unroll
  for (int G = 0; G < 4; ++G) {
    z[G] += __shfl_xor(z[G], 16);
    z[G] += __shfl_xor(z[G], 32);
  }
  if (lane < 16) {
#pragma unroll
    for (int G = 0; G < 4; ++G) {
      out[bbase + G * 16 + lane] = 1.0f / (1.0f + __expf(-z[G]));
    }
  }
}

// ---------------------------------------------------------------------------
// ws layout: Ure[65536] f32 | Uim[65536] f32 | Af[65536] bf16  = 640 KB.
// ---------------------------------------------------------------------------
extern "C" void kernel_launch(void* const* d_in, const int* in_sizes, int n_in,
                              void* d_out, int out_size, void* d_ws, size_t ws_size,
                              hipStream_t stream) {
  const float* x = (const float*)d_in[0];
  const float* params = (const float*)d_in[1];
  float* out = (float*)d_out;
  float* Ure = (float*)d_ws;
  float* Uim = Ure + DIM * DIM;
  short* Af = (short*)(Uim + DIM * DIM);

  build_U<<<DIM, 64, 0, stream>>>(params, Ure, Uim);
  build_A<<<DIM, 1024, 0, stream>>>(Ure, Uim, Af);

  const int B = in_sizes[0] / NQ;  // 131072
  qcnn_mfma<<<B / 64, 64, 0, stream>>>(x, Af, out);
}

// Round 8
// 95.263 us; speedup vs baseline: 1.0848x; 1.0848x over previous
//
#include <hip/hip_runtime.h>
#include <stdint.h>

#define DIM 256
#define NQ 8
#define NLAYERS 3
#define NPAIRS 4

typedef short bf16x8 __attribute__((ext_vector_type(8)));
typedef float f32x4 __attribute__((ext_vector_type(4)));

__device__ __forceinline__ unsigned short f2bf(float f) {
  uint32_t x = __builtin_bit_cast(uint32_t, f);
  uint32_t r = (x + 0x7FFFu + ((x >> 16) & 1u)) >> 16;  // RNE
  return (unsigned short)r;
}

// ---------------------------------------------------------------------------
// Kernel 1: build U (256x256 complex fp32), barrier-free, one WAVE per basis
// column, one column per 64-thread block. Lane holds 4 amplitudes
// a = r*64 + lane. Wire w <-> bit (7-w) of a: wire0 -> r bit1, wire1 -> r
// bit0 (in-register), wire2..7 -> lane bits 5..0 (shfl_xor).
// Algebra verified rounds 6-7 (passed, absmax unchanged).
// ---------------------------------------------------------------------------
__global__ __launch_bounds__(64) void build_U(const float* __restrict__ params,
                                              float* __restrict__ Ure,
                                              float* __restrict__ Uim) {
  const int lane = threadIdx.x;
  const int col = blockIdx.x;

  float ar[4], ai[4];
#pragma unroll
  for (int r = 0; r < 4; ++r) {
    ar[r] = (r * 64 + lane == col) ? 1.0f : 0.0f;
    ai[r] = 0.0f;
  }

  for (int layer = 0; layer < NLAYERS; ++layer) {
#pragma unroll
    for (int p = 0; p < NPAIRS; ++p) {
      const int base = (layer * NPAIRS + p) * 4;
      const float p0 = params[base + 0], p1 = params[base + 1];
      const float p2 = params[base + 2], p3 = params[base + 3];
      const int czm = (p == 1) ? 32 : (p == 2) ? 8 : 2;   // ctrl / RZ_i bit
      const int txr = (p == 1) ? 16 : (p == 2) ? 4 : 1;   // target xor / bit

      { // RZ(p0) on wire i = 2p
        float s0, c0;
        __sincosf(0.5f * p0, &s0, &c0);
        if (p == 0) {
#pragma unroll
          for (int r = 0; r < 4; ++r) {
            const float sg = (r >= 2) ? s0 : -s0;  // r bit1
            const float nr = ar[r] * c0 - ai[r] * sg;
            ai[r] = ar[r] * sg + ai[r] * c0;
            ar[r] = nr;
          }
        } else {
          const float sg = (lane & czm) ? s0 : -s0;
#pragma unroll
          for (int r = 0; r < 4; ++r) {
            const float nr = ar[r] * c0 - ai[r] * sg;
            ai[r] = ar[r] * sg + ai[r] * c0;
            ar[r] = nr;
          }
        }
      }
      { // RX(p1) on wire j = 2p+1
        float s0, c0;
        __sincosf(0.5f * p1, &s0, &c0);
        if (p == 0) {  // partner r^1
          float nr[4], ni[4];
#pragma unroll
          for (int r = 0; r < 4; ++r) {
            nr[r] = c0 * ar[r] + s0 * ai[r ^ 1];
            ni[r] = c0 * ai[r] - s0 * ar[r ^ 1];
          }
#pragma unroll
          for (int r = 0; r < 4; ++r) { ar[r] = nr[r]; ai[r] = ni[r]; }
        } else {  // partner lane^txr
#pragma unroll
          for (int r = 0; r < 4; ++r) {
            const float pr = __shfl_xor(ar[r], txr);
            const float pi = __shfl_xor(ai[r], txr);
            ar[r] = c0 * ar[r] + s0 * pi;
            ai[r] = c0 * ai[r] - s0 * pr;
          }
        }
      }
      { // CNOT(i -> j)
        if (p == 0) {  // ctrl r bit1: swap amp[2] <-> amp[3]
          const float tr = ar[2], ti = ai[2];
          ar[2] = ar[3]; ai[2] = ai[3];
          ar[3] = tr;    ai[3] = ti;
        } else {
#pragma unroll
          for (int r = 0; r < 4; ++r) {
            const float vr = __shfl_xor(ar[r], txr);
            const float vi = __shfl_xor(ai[r], txr);
            ar[r] = (lane & czm) ? vr : ar[r];
            ai[r] = (lane & czm) ? vi : ai[r];
          }
        }
      }
      { // RZ(p2) on wire j
        float s0, c0;
        __sincosf(0.5f * p2, &s0, &c0);
        if (p == 0) {
#pragma unroll
          for (int r = 0; r < 4; ++r) {
            const float sg = (r & 1) ? s0 : -s0;  // r bit0
            const float nr = ar[r] * c0 - ai[r] * sg;
            ai[r] = ar[r] * sg + ai[r] * c0;
            ar[r] = nr;
          }
        } else {
          const float sg = (lane & txr) ? s0 : -s0;
#pragma unroll
          for (int r = 0; r < 4; ++r) {
            const float nr = ar[r] * c0 - ai[r] * sg;
            ai[r] = ar[r] * sg + ai[r] * c0;
            ar[r] = nr;
          }
        }
      }
      { // RX(p3) on wire j
        float s0, c0;
        __sincosf(0.5f * p3, &s0, &c0);
        if (p == 0) {
          float nr[4], ni[4];
#pragma unroll
          for (int r = 0; r < 4; ++r) {
            nr[r] = c0 * ar[r] + s0 * ai[r ^ 1];
            ni[r] = c0 * ai[r] - s0 * ar[r ^ 1];
          }
#pragma unroll
          for (int r = 0; r < 4; ++r) { ar[r] = nr[r]; ai[r] = ni[r]; }
        } else {
#pragma unroll
          for (int r = 0; r < 4; ++r) {
            const float pr = __shfl_xor(ar[r], txr);
            const float pi = __shfl_xor(ai[r], txr);
            ar[r] = c0 * ar[r] + s0 * pi;
            ai[r] = c0 * ai[r] - s0 * pr;
          }
        }
      }
    }
  }
#pragma unroll
  for (int r = 0; r < 4; ++r) {
    Ure[(r * 64 + lane) * DIM + col] = ar[r];
    Uim[(r * 64 + lane) * DIM + col] = ai[r];
  }
}

// ---------------------------------------------------------------------------
// Kernel 2: A[n][k] = Re(U^H D U)[n][k], bf16, MFMA A-operand fragment order
// (verified rounds 2-7):
//   elem(n,k) -> ((((n>>4)*8 + (k>>5))*4 + ((k>>3)&3))*16 + (n&15))*8 + (k&7)
// 1024 threads/block: 4 m-chunks in parallel + LDS reduce.
// ---------------------------------------------------------------------------
__global__ __launch_bounds__(1024) void build_A(const float* __restrict__ Ure,
                                                const float* __restrict__ Uim,
                                                short* __restrict__ Af) {
  __shared__ float partial[4][DIM];
  const int n = blockIdx.x;
  const int kk = threadIdx.x & 255;
  const int mc = threadIdx.x >> 8;  // 0..3
  float acc = 0.0f;
  for (int m = mc * 64; m < mc * 64 + 64; ++m) {
    const float sgn = (m < 128) ? 1.0f : -1.0f;
    const float ukr = sgn * Ure[m * DIM + n];
    const float uki = sgn * Uim[m * DIM + n];
    acc = fmaf(ukr, Ure[m * DIM + kk], acc);
    acc = fmaf(uki, Uim[m * DIM + kk], acc);
  }
  partial[mc][kk] = acc;
  __syncthreads();
  if (mc == 0) {
    const float v = partial[0][kk] + partial[1][kk] + partial[2][kk] + partial[3][kk];
    const int off =
        ((((n >> 4) * 8 + (kk >> 5)) * 4 + ((kk >> 3) & 3)) * 16 + (n & 15)) * 8 +
        (kk & 7);
    Af[off] = (short)f2bf(v);
  }
}

// ---------------------------------------------------------------------------
// Kernel 3 (MFMA, 1-wave blocks, 4 batch-groups = 64 batch/wave, v4):
// v4 = round-6 occupancy attr + round-7 chunking; the two prior failures had
// complementary, counter-identified causes:
//   round 6: waves_per_eu(1), 32 KB chunks -> no spill, but LDS capped
//            residency at 5 blocks/CU (grid wants 8) -> latency exposed.
//   round 7: waves_per_eu(2) capped VGPR at 128 vs ~200 live -> 38 MB spill.
// v4: 16 KB chunks (LDS allows 10/CU) + waves_per_eu(1) (VGPR cap 512,
// expect ~200-240 alloc, spill-free) -> 2 waves/SIMD, 8 blocks/CU = grid/CU.
// Floor: max(staging 268MB@L2 ~8us, LDS 268MB ~4us, MFMA ~7us) ~ 9-12us.
// HARD TRIGGER: if total >= 89.7us, revert to round-5 qcnn next round.
// ---------------------------------------------------------------------------
__global__ __launch_bounds__(64)
__attribute__((amdgpu_waves_per_eu(1)))
void qcnn_mfma(const float* __restrict__ x,
               const short* __restrict__ Af,
               float* __restrict__ out) {
  __shared__ short sA[8192];  // one 16 KB chunk: 32 n-rows x 256 k (bf16)
  const int lane = threadIdx.x;
  const int c = lane & 15;
  const int q = lane >> 4;
  const int lo = q & 1;
  const int hi = (q >> 1) & 1;
  const int bbase = blockIdx.x * 64;
  const char* Abytes = (const char*)Af;
  char* sAbytes = (char*)sA;

  // stage chunk 0 (overlaps with psi setup below)
#pragma unroll
  for (int i = 0; i < 16; ++i) {
    __builtin_amdgcn_global_load_lds(
        (const __attribute__((address_space(1))) uint32_t*)(Abytes + i * 1024 +
                                                            lane * 16),
        (__attribute__((address_space(3))) uint32_t*)(sAbytes + i * 1024), 16,
        0, 0);
  }

  bf16x8 psi[4][8];
  float ccg[4][4], ssg[4][4], hd[4][4];
#pragma unroll
  for (int G = 0; G < 4; ++G) {
    const int b = bbase + G * 16 + c;
    const float4* xv = (const float4*)(x + (size_t)b * 8);
    const float4 x0 = xv[0];
    const float4 x1 = xv[1];
    const float xs[8] = {x0.x, x0.y, x0.z, x0.w, x1.x, x1.y, x1.z, x1.w};
    float cc[8], ss[8];
#pragma unroll
    for (int u = 0; u < 8; ++u) {
      cc[u] = __cosf(0.5f * xs[u]);
      ss[u] = __sinf(0.5f * xs[u]);
    }
    // hs[j] = h[8*lo + j]
    float hs[8];
    {
      const float a = lo ? ss[4] : cc[4];
      const float b0 = a * cc[5], b1 = a * ss[5];
      const float c0 = b0 * cc[6], c1 = b0 * ss[6];
      const float c2 = b1 * cc[6], c3 = b1 * ss[6];
      hs[0] = c0 * cc[7]; hs[1] = c0 * ss[7];
      hs[2] = c1 * cc[7]; hs[3] = c1 * ss[7];
      hs[4] = c2 * cc[7]; hs[5] = c2 * ss[7];
      hs[6] = c3 * cc[7]; hs[7] = c3 * ss[7];
    }
    // gk[t] = g[2t + hi]
    float gk[8];
    {
      const float g3 = hi ? ss[3] : cc[3];
      const float d0 = cc[2] * g3, d1 = ss[2] * g3;
      const float e0 = cc[1] * d0, e1 = cc[1] * d1;
      const float e2 = ss[1] * d0, e3 = ss[1] * d1;
      gk[0] = cc[0] * e0; gk[1] = cc[0] * e1;
      gk[2] = cc[0] * e2; gk[3] = cc[0] * e3;
      gk[4] = ss[0] * e0; gk[5] = ss[0] * e1;
      gk[6] = ss[0] * e2; gk[7] = ss[0] * e3;
    }
    // hd[r] = h[8*hi + 4*lo + r]
    {
      const float head = (hi ? ss[4] : cc[4]) * (lo ? ss[5] : cc[5]);
      const float h0 = head * cc[6], h1 = head * ss[6];
      hd[G][0] = h0 * cc[7]; hd[G][1] = h0 * ss[7];
      hd[G][2] = h1 * cc[7]; hd[G][3] = h1 * ss[7];
    }
    // psi frag for k-block t: element j is psi_b[32t + 8q + j] = gk[t]*hs[j]
#pragma unroll
    for (int t = 0; t < 8; ++t) {
#pragma unroll
      for (int j = 0; j < 8; ++j) psi[G][t][j] = (short)f2bf(gk[t] * hs[j]);
    }
#pragma unroll
    for (int u = 0; u < 4; ++u) { ccg[G][u] = cc[u]; ssg[G][u] = ss[u]; }
  }

  float z[4] = {0.0f, 0.0f, 0.0f, 0.0f};

#pragma unroll
  for (int nc = 0; nc < 8; ++nc) {  // 8 chunks x 32 n-rows
    if (nc) {
      __syncthreads();  // WAR: prior ds_reads done before DMA overwrite
#pragma unroll
      for (int i = 0; i < 16; ++i) {
        __builtin_amdgcn_global_load_lds(
            (const __attribute__((address_space(1))) uint32_t*)(
                Abytes + nc * 16384 + i * 1024 + lane * 16),
            (__attribute__((address_space(3))) uint32_t*)(sAbytes + i * 1024),
            16, 0, 0);
      }
    }
    __syncthreads();  // RAW: staged chunk visible

#pragma unroll
    for (int nt = 0; nt < 2; ++nt) {
      f32x4 a0 = {0.f, 0.f, 0.f, 0.f};
      f32x4 a1 = {0.f, 0.f, 0.f, 0.f};
      f32x4 a2 = {0.f, 0.f, 0.f, 0.f};
      f32x4 a3 = {0.f, 0.f, 0.f, 0.f};
#pragma unroll
      for (int t = 0; t < 8; ++t) {
        const bf16x8 af =
            *(const bf16x8*)(sA + (nt * 4096 + t * 512 + lane * 8));
        a0 = __builtin_amdgcn_mfma_f32_16x16x32_bf16(af, psi[0][t], a0, 0, 0, 0);
        a1 = __builtin_amdgcn_mfma_f32_16x16x32_bf16(af, psi[1][t], a1, 0, 0, 0);
        a2 = __builtin_amdgcn_mfma_f32_16x16x32_bf16(af, psi[2][t], a2, 0, 0, 0);
        a3 = __builtin_amdgcn_mfma_f32_16x16x32_bf16(af, psi[3][t], a3, 0, 0, 0);
      }
      // rows n = (nc*2+nt)*16 + q*4 + r -> psi[b][n] = g[nc*2+nt] * hd[r]
      const int gi = nc * 2 + nt;  // compile-time
#pragma unroll
      for (int G = 0; G < 4; ++G) {
        const f32x4 av = (G == 0) ? a0 : (G == 1) ? a1 : (G == 2) ? a2 : a3;
        const float gv = ((gi & 8) ? ssg[G][0] : ccg[G][0]) *
                         ((gi & 4) ? ssg[G][1] : ccg[G][1]) *
                         ((gi & 2) ? ssg[G][2] : ccg[G][2]) *
                         ((gi & 1) ? ssg[G][3] : ccg[G][3]);
        const float dot = hd[G][0] * av[0] + hd[G][1] * av[1] +
                          hd[G][2] * av[2] + hd[G][3] * av[3];
        z[G] = fmaf(gv, dot, z[G]);
      }
    }
  }

  // reduce across the 4 q-groups (same col lives in lanes c, c+16, c+32, c+48)
#pragma unroll
  for (int G = 0; G < 4; ++G) {
    z[G] += __shfl_xor(z[G], 16);
    z[G] += __shfl_xor(z[G], 32);
  }
  if (lane < 16) {
#pragma unroll
    for (int G = 0; G < 4; ++G) {
      out[bbase + G * 16 + lane] = 1.0f / (1.0f + __expf(-z[G]));
    }
  }
}

// ---------------------------------------------------------------------------
// ws layout: Ure[65536] f32 | Uim[65536] f32 | Af[65536] bf16  = 640 KB.
// ---------------------------------------------------------------------------
extern "C" void kernel_launch(void* const* d_in, const int* in_sizes, int n_in,
                              void* d_out, int out_size, void* d_ws, size_t ws_size,
                              hipStream_t stream) {
  const float* x = (const float*)d_in[0];
  const float* params = (const float*)d_in[1];
  float* out = (float*)d_out;
  float* Ure = (float*)d_ws;
  float* Uim = Ure + DIM * DIM;
  short* Af = (short*)(Uim + DIM * DIM);

  build_U<<<DIM, 64, 0, stream>>>(params, Ure, Uim);
  build_A<<<DIM, 1024, 0, stream>>>(Ure, Uim, Af);

  const int B = in_sizes[0] / NQ;  // 131072
  qcnn_mfma<<<B / 64, 64, 0, stream>>>(x, Af, out);
}